// Round 4
// baseline (50.844 us; speedup 1.0000x reference)
//
#include <hip/hip_runtime.h>
#include <stdint.h>

#define NV 4096

typedef __attribute__((ext_vector_type(8))) short bf16x8;
typedef __attribute__((ext_vector_type(4))) float f32x4;

__device__ __forceinline__ unsigned short f2bf(float f) {
  union { float f; unsigned int u; } v; v.f = f;
  unsigned int r = v.u + 0x7FFF + ((v.u >> 16) & 1);  // RNE
  return (unsigned short)(r >> 16);
}

// fused prep: blocks 0..2047 convert feature_map f32->bf16 (4 elems/thread);
// blocks 2048..2319 permute weights (64 x 1088, f=c*17+k) -> Wb[k][o][c] bf16.
__global__ __launch_bounds__(256)
void prep(const float* __restrict__ fm, const float* __restrict__ w,
          unsigned short* __restrict__ fmb, unsigned short* __restrict__ wb) {
  int blk = blockIdx.x;
  if (blk < 2048) {
    int i = (blk * 256 + threadIdx.x) * 4;
    float4 v = *(const float4*)(fm + i);
    ushort4 o;
    o.x = f2bf(v.x); o.y = f2bf(v.y); o.z = f2bf(v.z); o.w = f2bf(v.w);
    *(ushort4*)(fmb + i) = o;
  } else {
    int t = (blk - 2048) * 256 + threadIdx.x;  // 0..69631 (= 17*64*64)
    int c = t & 63;
    int o = (t >> 6) & 63;
    int k = t >> 12;
    wb[t] = f2bf(w[o * 1088 + c * 17 + k]);
  }
}

// Barrier-light gather-GEMM, K-split x2 for occupancy.
// Block = 4 waves (256 thr): 2 row-groups x 2 K-halves; covers 32 vertices x 64 ch.
// Grid = 1024 (8 batches x 128 row-tiles) -> 4 blocks/CU -> 4 waves/SIMD.
// Register X/Y pipeline pinned with sched_barrier(0) at phase granularity.
__global__ __launch_bounds__(256, 4)
void conv_main(const int* __restrict__ nbr, const unsigned short* __restrict__ fmb,
               const unsigned short* __restrict__ wb, const float* __restrict__ bias,
               float* __restrict__ out) {
  __shared__ float sRed[2][16][64];   // [row-group][acc elem][lane]

  const int bid = blockIdx.x;
  const int b = bid & 7;              // batch == XCD (bijective: 128 tiles/batch)
  const int t = bid >> 3;             // 0..127 row-tile
  const int tid = threadIdx.x;
  const int lane = tid & 63;
  const int lm = lane & 15;
  const int lk = lane >> 4;
  const int w = tid >> 6;
  const int g = w >> 1;               // row-group 0..1
  const int h = w & 1;                // K-half 0..1

  const int row = t * 32 + g * 16 + lm;
  const bf16x8* fb = (const bf16x8*)(fmb + (size_t)b * NV * 64);
  const bf16x8* wq = (const bf16x8*)wb + (lm * 8 + lk);
  const int4* nr = (const int4*)(nbr + ((size_t)b * NV + row) * 16);

  f32x4 acc0 = {0.f, 0.f, 0.f, 0.f}, acc1 = {0.f, 0.f, 0.f, 0.f};
  f32x4 acc2 = {0.f, 0.f, 0.f, 0.f}, acc3 = {0.f, 0.f, 0.f, 0.f};

  bf16x8 A0X, A1X, B00X, B01X, B10X, B11X, B20X, B21X, B30X, B31X;
  bf16x8 A0Y, A1Y, B00Y, B01Y, B10Y, B11Y, B20Y, B21Y, B30Y, B31Y;

#define SB __builtin_amdgcn_sched_barrier(0)

#define LOADS(S, K, SV) {                                    \
    const bf16x8* p_ = fb + (size_t)(SV) * 8;                \
    A0##S = p_[lk];                                          \
    A1##S = p_[4 + lk];                                      \
    const bf16x8* q_ = wq + (K) * 512;                       \
    B00##S = q_[0];   B01##S = q_[4];                        \
    B10##S = q_[128]; B11##S = q_[132];                      \
    B20##S = q_[256]; B21##S = q_[260];                      \
    B30##S = q_[384]; B31##S = q_[388];                      \
  }

#define MM(S) {                                                                   \
    acc0 = __builtin_amdgcn_mfma_f32_16x16x32_bf16(A0##S, B00##S, acc0, 0, 0, 0); \
    acc1 = __builtin_amdgcn_mfma_f32_16x16x32_bf16(A0##S, B10##S, acc1, 0, 0, 0); \
    acc2 = __builtin_amdgcn_mfma_f32_16x16x32_bf16(A0##S, B20##S, acc2, 0, 0, 0); \
    acc3 = __builtin_amdgcn_mfma_f32_16x16x32_bf16(A0##S, B30##S, acc3, 0, 0, 0); \
    acc0 = __builtin_amdgcn_mfma_f32_16x16x32_bf16(A1##S, B01##S, acc0, 0, 0, 0); \
    acc1 = __builtin_amdgcn_mfma_f32_16x16x32_bf16(A1##S, B11##S, acc1, 0, 0, 0); \
    acc2 = __builtin_amdgcn_mfma_f32_16x16x32_bf16(A1##S, B21##S, acc2, 0, 0, 0); \
    acc3 = __builtin_amdgcn_mfma_f32_16x16x32_bf16(A1##S, B31##S, acc3, 0, 0, 0); \
  }

  if (h == 0) {
    // slots 0..8: self + neighbors 0..7
    const int4 iva = nr[0], ivb = nr[1];
    LOADS(X, 0, row); SB;
    LOADS(Y, 1, iva.x); SB;
    MM(X); SB; LOADS(X, 2, iva.y); SB;
    MM(Y); SB; LOADS(Y, 3, iva.z); SB;
    MM(X); SB; LOADS(X, 4, iva.w); SB;
    MM(Y); SB; LOADS(Y, 5, ivb.x); SB;
    MM(X); SB; LOADS(X, 6, ivb.y); SB;
    MM(Y); SB; LOADS(Y, 7, ivb.z); SB;
    MM(X); SB; LOADS(X, 8, ivb.w); SB;
    MM(Y); SB;
    MM(X);
  } else {
    // slots 9..16: neighbors 8..15
    const int4 iva = nr[2], ivb = nr[3];
    LOADS(X, 9, iva.x); SB;
    LOADS(Y, 10, iva.y); SB;
    MM(X); SB; LOADS(X, 11, iva.z); SB;
    MM(Y); SB; LOADS(Y, 12, iva.w); SB;
    MM(X); SB; LOADS(X, 13, ivb.x); SB;
    MM(Y); SB; LOADS(Y, 14, ivb.y); SB;
    MM(X); SB; LOADS(X, 15, ivb.z); SB;
    MM(Y); SB; LOADS(Y, 16, ivb.w); SB;
    MM(X); SB;
    MM(Y);
  }

#undef MM
#undef LOADS
#undef SB

  if (h == 1) {
    #pragma unroll
    for (int r = 0; r < 4; ++r) {
      sRed[g][r][lane]      = acc0[r];
      sRed[g][4 + r][lane]  = acc1[r];
      sRed[g][8 + r][lane]  = acc2[r];
      sRed[g][12 + r][lane] = acc3[r];
    }
  }
  __syncthreads();
  if (h == 0) {
    #pragma unroll
    for (int r = 0; r < 4; ++r) {
      acc0[r] += sRed[g][r][lane];
      acc1[r] += sRed[g][4 + r][lane];
      acc2[r] += sRed[g][8 + r][lane];
      acc3[r] += sRed[g][12 + r][lane];
    }
    const float bv0 = bias[lm];
    const float bv1 = bias[16 + lm];
    const float bv2 = bias[32 + lm];
    const float bv3 = bias[48 + lm];
    float* op = out + (size_t)b * NV * 64;
    const int gv = t * 32 + g * 16 + lk * 4;
    #pragma unroll
    for (int r = 0; r < 4; ++r) {
      float* orow = op + (size_t)(gv + r) * 64;
      orow[lm]      = fmaxf(acc0[r] + bv0, 0.f);
      orow[16 + lm] = fmaxf(acc1[r] + bv1, 0.f);
      orow[32 + lm] = fmaxf(acc2[r] + bv2, 0.f);
      orow[48 + lm] = fmaxf(acc3[r] + bv3, 0.f);
    }
  }
}

extern "C" void kernel_launch(void* const* d_in, const int* in_sizes, int n_in,
                              void* d_out, int out_size, void* d_ws, size_t ws_size,
                              hipStream_t stream) {
  const int* nbr = (const int*)d_in[0];
  // d_in[1] = vertices (unused by the reference computation)
  const float* fm = (const float*)d_in[2];
  const float* w = (const float*)d_in[3];
  const float* bias = (const float*)d_in[4];
  float* out = (float*)d_out;

  unsigned short* fmb = (unsigned short*)d_ws;          // 8*4096*64 bf16 = 4 MB
  unsigned short* wb = fmb + (size_t)8 * NV * 64;       // 17*64*64 bf16

  prep<<<2320, 256, 0, stream>>>(fm, w, fmb, wb);
  conv_main<<<1024, 256, 0, stream>>>(nbr, fmb, wb, bias, out);
}

// Round 5
// 22.994 us; speedup vs baseline: 2.2112x; 2.2112x over previous
//
#include <hip/hip_runtime.h>
#include <stdint.h>

#define NV 4096

typedef __attribute__((ext_vector_type(8))) short bf16x8;
typedef __attribute__((ext_vector_type(4))) float f32x4;

__device__ __forceinline__ unsigned short f2bf(float f) {
  union { float f; unsigned int u; } v; v.f = f;
  unsigned int r = v.u + 0x7FFF + ((v.u >> 16) & 1);  // RNE
  return (unsigned short)(r >> 16);
}

// fused prep: blocks 0..1023 convert feature_map f32->bf16 (8 elems/thread);
// blocks 1024..1295 permute weights (64 x 1088, f=c*17+k) -> Wb[k][o][c] bf16.
__global__ __launch_bounds__(256)
void prep(const float* __restrict__ fm, const float* __restrict__ w,
          unsigned short* __restrict__ fmb, unsigned short* __restrict__ wb) {
  int blk = blockIdx.x;
  if (blk < 1024) {
    int i = (blk * 256 + threadIdx.x) * 8;
    float4 v0 = *(const float4*)(fm + i);
    float4 v1 = *(const float4*)(fm + i + 4);
    ushort4 o0, o1;
    o0.x = f2bf(v0.x); o0.y = f2bf(v0.y); o0.z = f2bf(v0.z); o0.w = f2bf(v0.w);
    o1.x = f2bf(v1.x); o1.y = f2bf(v1.y); o1.z = f2bf(v1.z); o1.w = f2bf(v1.w);
    *(ushort4*)(fmb + i) = o0;
    *(ushort4*)(fmb + i + 4) = o1;
  } else {
    int t = (blk - 1024) * 256 + threadIdx.x;  // 0..69631 (= 17*64*64)
    int c = t & 63;
    int o = (t >> 6) & 63;
    int k = t >> 12;
    wb[t] = f2bf(w[o * 1088 + c * 17 + k]);
  }
}

// Gather-GEMM: weights fully LDS-resident (139KB, staged once, coalesced),
// A gathered straight to VGPR fragments (only divergent traffic).
// Block = 512 thr = 8 waves = 4 row-groups x 2 K-halves; 128 rows/block.
// Grid 256 = 1 block/CU. Barrier-free main loop, A depth-3 / B depth-2 pipeline.
__global__ __launch_bounds__(512, 2)
void conv_main(const int* __restrict__ nbr, const unsigned short* __restrict__ fmb,
               const unsigned short* __restrict__ wb, const float* __restrict__ bias,
               float* __restrict__ out) {
  __shared__ unsigned short smem[17 * 4096];  // 17 slots x 8KB = 139264 B

  const int bid = blockIdx.x;
  const int b = bid & 7;                // batch == XCD
  const int tile = bid >> 3;            // 0..31
  const int tid = threadIdx.x;
  const int lane = tid & 63;
  const int lm = lane & 15;
  const int lk = lane >> 4;
  const int w8 = tid >> 6;              // wave 0..7
  const int rg = w8 >> 1;               // row-group 0..3 (32 rows each)
  const int h = w8 & 1;                 // K-half

  const int rbase = tile * 128 + rg * 32;
  const int row0 = rbase + lm;
  const int row1 = rbase + 16 + lm;

  const bf16x8* fb = (const bf16x8*)(fmb + (size_t)b * NV * 64);

  // this K-half's 8 neighbor indices for both owned rows
  const int4* n0 = (const int4*)(nbr + ((size_t)b * NV + row0) * 16) + h * 2;
  const int4* n1 = (const int4*)(nbr + ((size_t)b * NV + row1) * 16) + h * 2;
  const int4 i0a = n0[0], i0b = n0[1];
  const int4 i1a = n1[0], i1b = n1[1];

  // swizzled LDS read offsets for B fragments (conflict-free ds_read_b128)
  const int off0 = lm * 128 + ((lk ^ (lm & 7)) << 4);
  const int off1 = off0 ^ 64;

  f32x4 acc00{0,0,0,0}, acc01{0,0,0,0}, acc02{0,0,0,0}, acc03{0,0,0,0};
  f32x4 acc10{0,0,0,0}, acc11{0,0,0,0}, acc12{0,0,0,0}, acc13{0,0,0,0};

  bf16x8 A0h0X, A0h1X, A1h0X, A1h1X;
  bf16x8 A0h0Y, A0h1Y, A1h0Y, A1h1Y;
  bf16x8 A0h0Z, A0h1Z, A1h0Z, A1h1Z;
  bf16x8 B0h0P, B1h0P, B2h0P, B3h0P, B0h1P, B1h1P, B2h1P, B3h1P;
  bf16x8 B0h0Q, B1h0Q, B2h0Q, B3h0Q, B0h1Q, B1h1Q, B2h1Q, B3h1Q;

#define SBR __builtin_amdgcn_sched_barrier(0)
#define MFMA __builtin_amdgcn_mfma_f32_16x16x32_bf16

#define LOADA(S, SV0, SV1) {                         \
    const bf16x8* p0_ = fb + (size_t)(SV0) * 8;      \
    const bf16x8* p1_ = fb + (size_t)(SV1) * 8;      \
    A0h0##S = p0_[lk];     A0h1##S = p0_[lk + 4];    \
    A1h0##S = p1_[lk];     A1h1##S = p1_[lk + 4];    \
  }

#define LOADB(S, KG) {                                          \
    const char* bp_ = ((const char*)smem) + (KG) * 8192;        \
    B0h0##S = *(const bf16x8*)(bp_ + 0 * 2048 + off0);          \
    B1h0##S = *(const bf16x8*)(bp_ + 1 * 2048 + off0);          \
    B2h0##S = *(const bf16x8*)(bp_ + 2 * 2048 + off0);          \
    B3h0##S = *(const bf16x8*)(bp_ + 3 * 2048 + off0);          \
    B0h1##S = *(const bf16x8*)(bp_ + 0 * 2048 + off1);          \
    B1h1##S = *(const bf16x8*)(bp_ + 1 * 2048 + off1);          \
    B2h1##S = *(const bf16x8*)(bp_ + 2 * 2048 + off1);          \
    B3h1##S = *(const bf16x8*)(bp_ + 3 * 2048 + off1);          \
  }

#define MM(SA, SB) {                                       \
    acc00 = MFMA(A0h0##SA, B0h0##SB, acc00, 0, 0, 0);      \
    acc01 = MFMA(A0h0##SA, B1h0##SB, acc01, 0, 0, 0);      \
    acc02 = MFMA(A0h0##SA, B2h0##SB, acc02, 0, 0, 0);      \
    acc03 = MFMA(A0h0##SA, B3h0##SB, acc03, 0, 0, 0);      \
    acc10 = MFMA(A1h0##SA, B0h0##SB, acc10, 0, 0, 0);      \
    acc11 = MFMA(A1h0##SA, B1h0##SB, acc11, 0, 0, 0);      \
    acc12 = MFMA(A1h0##SA, B2h0##SB, acc12, 0, 0, 0);      \
    acc13 = MFMA(A1h0##SA, B3h0##SB, acc13, 0, 0, 0);      \
    acc00 = MFMA(A0h1##SA, B0h1##SB, acc00, 0, 0, 0);      \
    acc01 = MFMA(A0h1##SA, B1h1##SB, acc01, 0, 0, 0);      \
    acc02 = MFMA(A0h1##SA, B2h1##SB, acc02, 0, 0, 0);      \
    acc03 = MFMA(A0h1##SA, B3h1##SB, acc03, 0, 0, 0);      \
    acc10 = MFMA(A1h1##SA, B0h1##SB, acc10, 0, 0, 0);      \
    acc11 = MFMA(A1h1##SA, B1h1##SB, acc11, 0, 0, 0);      \
    acc12 = MFMA(A1h1##SA, B2h1##SB, acc12, 0, 0, 0);      \
    acc13 = MFMA(A1h1##SA, B3h1##SB, acc13, 0, 0, 0);      \
  }

  // ---- prologue: issue A for local slots 0,1 (latency hides under staging)
  const int sv00 = h ? i0a.x : row0;   const int sv10 = h ? i1a.x : row1;
  const int sv01 = h ? i0a.y : i0a.x;  const int sv11 = h ? i1a.y : i1a.x;
  const int sv02 = h ? i0a.z : i0a.y;  const int sv12 = h ? i1a.z : i1a.y;

  LOADA(X, sv00, sv10);
  LOADA(Y, sv01, sv11);

  // ---- stage all 17 weight slots into LDS, source pre-swizzled (rule #21)
  #pragma unroll
  for (int i = 0; i < 17; ++i) {
    int t = i * 512 + tid;
    int slot = t >> 9;
    int r = (t >> 3) & 63;
    int sl = t & 7;
    int seg = sl ^ (r & 7);
    const unsigned short* src = wb + (size_t)slot * 4096 + r * 64 + seg * 8;
    unsigned short* dst = smem + (size_t)t * 8;
    __builtin_amdgcn_global_load_lds(
        (const __attribute__((address_space(1))) void*)src,
        (__attribute__((address_space(3))) void*)dst, 16, 0, 0);
  }
  __syncthreads();

  LOADA(Z, sv02, sv12);
  if (h == 0) { LOADB(P, 0); } else { LOADB(P, 9); }

  if (h == 0) {
    // slots 0..8 : self + neighbors 0..7
    LOADB(Q, 1); SBR; MM(X, P); SBR; LOADA(X, i0a.z, i1a.z); SBR;
    LOADB(P, 2); SBR; MM(Y, Q); SBR; LOADA(Y, i0a.w, i1a.w); SBR;
    LOADB(Q, 3); SBR; MM(Z, P); SBR; LOADA(Z, i0b.x, i1b.x); SBR;
    LOADB(P, 4); SBR; MM(X, Q); SBR; LOADA(X, i0b.y, i1b.y); SBR;
    LOADB(Q, 5); SBR; MM(Y, P); SBR; LOADA(Y, i0b.z, i1b.z); SBR;
    LOADB(P, 6); SBR; MM(Z, Q); SBR; LOADA(Z, i0b.w, i1b.w); SBR;
    LOADB(Q, 7); SBR; MM(X, P); SBR;
    LOADB(P, 8); SBR; MM(Y, Q); SBR;
    MM(Z, P);
  } else {
    // slots 9..16 : neighbors 8..15
    LOADB(Q, 10); SBR; MM(X, P); SBR; LOADA(X, i0a.w, i1a.w); SBR;
    LOADB(P, 11); SBR; MM(Y, Q); SBR; LOADA(Y, i0b.x, i1b.x); SBR;
    LOADB(Q, 12); SBR; MM(Z, P); SBR; LOADA(Z, i0b.y, i1b.y); SBR;
    LOADB(P, 13); SBR; MM(X, Q); SBR; LOADA(X, i0b.z, i1b.z); SBR;
    LOADB(Q, 14); SBR; MM(Y, P); SBR; LOADA(Y, i0b.w, i1b.w); SBR;
    LOADB(P, 15); SBR; MM(Z, Q); SBR;
    LOADB(Q, 16); SBR; MM(X, P); SBR;
    MM(Y, Q);
  }

#undef MM
#undef LOADB
#undef LOADA
#undef MFMA
#undef SBR

  // ---- combine K-halves through LDS (reuses dead B region), then epilogue
  __syncthreads();   // all B reads complete
  if (h == 1) {
    float* rp = (float*)smem + rg * 2048 + lane * 4;
    *(f32x4*)(rp + 0 * 256) = acc00;
    *(f32x4*)(rp + 1 * 256) = acc01;
    *(f32x4*)(rp + 2 * 256) = acc02;
    *(f32x4*)(rp + 3 * 256) = acc03;
    *(f32x4*)(rp + 4 * 256) = acc10;
    *(f32x4*)(rp + 5 * 256) = acc11;
    *(f32x4*)(rp + 6 * 256) = acc12;
    *(f32x4*)(rp + 7 * 256) = acc13;
  }
  __syncthreads();
  if (h == 0) {
    const float* rp = (const float*)smem + rg * 2048 + lane * 4;
    acc00 += *(const f32x4*)(rp + 0 * 256);
    acc01 += *(const f32x4*)(rp + 1 * 256);
    acc02 += *(const f32x4*)(rp + 2 * 256);
    acc03 += *(const f32x4*)(rp + 3 * 256);
    acc10 += *(const f32x4*)(rp + 4 * 256);
    acc11 += *(const f32x4*)(rp + 5 * 256);
    acc12 += *(const f32x4*)(rp + 6 * 256);
    acc13 += *(const f32x4*)(rp + 7 * 256);

    const float bv0 = bias[lm];
    const float bv1 = bias[16 + lm];
    const float bv2 = bias[32 + lm];
    const float bv3 = bias[48 + lm];
    float* op = out + (size_t)b * NV * 64;
    #pragma unroll
    for (int m = 0; m < 2; ++m) {
      const int gv = rbase + m * 16 + lk * 4;
      #pragma unroll
      for (int r = 0; r < 4; ++r) {
        float* orow = op + (size_t)(gv + r) * 64;
        if (m == 0) {
          orow[lm]      = fmaxf(acc00[r] + bv0, 0.f);
          orow[16 + lm] = fmaxf(acc01[r] + bv1, 0.f);
          orow[32 + lm] = fmaxf(acc02[r] + bv2, 0.f);
          orow[48 + lm] = fmaxf(acc03[r] + bv3, 0.f);
        } else {
          orow[lm]      = fmaxf(acc10[r] + bv0, 0.f);
          orow[16 + lm] = fmaxf(acc11[r] + bv1, 0.f);
          orow[32 + lm] = fmaxf(acc12[r] + bv2, 0.f);
          orow[48 + lm] = fmaxf(acc13[r] + bv3, 0.f);
        }
      }
    }
  }
}

extern "C" void kernel_launch(void* const* d_in, const int* in_sizes, int n_in,
                              void* d_out, int out_size, void* d_ws, size_t ws_size,
                              hipStream_t stream) {
  const int* nbr = (const int*)d_in[0];
  // d_in[1] = vertices (unused by the reference computation)
  const float* fm = (const float*)d_in[2];
  const float* w = (const float*)d_in[3];
  const float* bias = (const float*)d_in[4];
  float* out = (float*)d_out;

  unsigned short* fmb = (unsigned short*)d_ws;          // 8*4096*64 bf16 = 4 MB
  unsigned short* wb = fmb + (size_t)8 * NV * 64;       // 17*64*64 bf16

  prep<<<1296, 256, 0, stream>>>(fm, w, fmb, wb);
  conv_main<<<256, 512, 0, stream>>>(nbr, fmb, wb, bias, out);
}